// Round 16
// baseline (80.935 us; speedup 1.0000x reference)
//
#include <hip/hip_runtime.h>

typedef __attribute__((ext_vector_type(8))) short bf16x8;
typedef __attribute__((ext_vector_type(4))) float f32x4;
typedef __attribute__((ext_vector_type(4))) float f4v;
typedef __attribute__((ext_vector_type(4))) unsigned short u16x4;

#define NB 16
#define NC 128
#define NN 16384
#define CHUNKS 32
#define KSTEPS 8

__device__ __forceinline__ unsigned int f2bf_pack(float lo, float hi) {
  unsigned int ulo = __float_as_uint(lo);
  unsigned int uhi = __float_as_uint(hi);
  ulo = (ulo + 0x7FFFu + ((ulo >> 16) & 1u)) >> 16;
  uhi = (uhi + 0x7FFFu + ((uhi >> 16) & 1u)) & 0xFFFF0000u;
  return ulo | uhi;
}

__device__ __forceinline__ unsigned short f2bf_one(float v) {
  unsigned int u = __float_as_uint(v);
  return (unsigned short)((u + 0x7FFFu + ((u >> 16) & 1u)) >> 16);
}

__device__ __forceinline__ float bf2f(unsigned short u) {
  return __uint_as_float(((unsigned int)u) << 16);
}

//==================== Kernel A: partial Gram per (batch, K-chunk) ====================
// r11 pipeline, reorganized into k-step PAIRS: both steps' loads issue back-to-back
// per task (adjacent 256-B windows of the same row -> 512-B DRAM page visits).
// MFMA order over k unchanged -> partials bitwise identical to r11/r15.
__global__ __launch_bounds__(256, 2)
void nlm_gram_kernel(const float* __restrict__ x, unsigned short* __restrict__ partials) {
  __shared__ __align__(16) char lds[2 * 128 * 64 * 2];  // 2 x 16 KiB k-step buffers
  const int t = threadIdx.x;
  const int g = blockIdx.x;
  const int b  = g / CHUNKS;
  const int ch = g % CHUNKS;
  const int lane = t & 63, wv = t >> 6, l15 = lane & 15, q = lane >> 4;

  const float* xb = x + (size_t)b * NC * NN + (size_t)ch * (KSTEPS * 64);

  f32x4 acc[2][8];
#pragma unroll
  for (int i = 0; i < 2; ++i)
#pragma unroll
    for (int j = 0; j < 8; ++j) acc[i][j] = (f32x4){0.f, 0.f, 0.f, 0.f};

  int srow[4], sseg[4];
#pragma unroll
  for (int i = 0; i < 4; ++i) { int id = t + 256 * i; srow[i] = id >> 3; sseg[i] = id & 7; }

  f4v pfA[4][2], pfB[4][2];

// Load steps KS and KS+1 together: per task, 4 adjacent instructions touch
// [c, c+512) of one row (c = KS*256 bytes) -> one 512-B page visit.
#define LOADPF2(KS)                                                          \
  {                                                                          \
    _Pragma("unroll") for (int i = 0; i < 4; ++i) {                          \
      const float* srcA = xb + (size_t)srow[i] * NN + (KS)*64 + sseg[i] * 8; \
      pfA[i][0] = *(const f4v*)srcA;                                         \
      pfA[i][1] = *(const f4v*)(srcA + 4);                                   \
      pfB[i][0] = *(const f4v*)(srcA + 64);                                  \
      pfB[i][1] = *(const f4v*)(srcA + 68);                                  \
    }                                                                        \
  }

#define PACKPF(PF, BUF)                                                     \
  {                                                                         \
    _Pragma("unroll") for (int i = 0; i < 4; ++i) {                         \
      uint4 pk;                                                             \
      pk.x = f2bf_pack(PF[i][0][0], PF[i][0][1]);                           \
      pk.y = f2bf_pack(PF[i][0][2], PF[i][0][3]);                           \
      pk.z = f2bf_pack(PF[i][1][0], PF[i][1][1]);                           \
      pk.w = f2bf_pack(PF[i][1][2], PF[i][1][3]);                           \
      int byte = (srow[i] * 128 + sseg[i] * 16) ^ ((srow[i] & 7) << 4);     \
      *(uint4*)((BUF) + byte) = pk;                                         \
    }                                                                       \
  }

#define MFMAPH(BUF)                                                                          \
  {                                                                                          \
    _Pragma("unroll") for (int kh = 0; kh < 2; ++kh) {                                       \
      const int kbyte = kh * 64 + q * 16;                                                    \
      int ra = wv * 32 + l15;                                                                \
      bf16x8 a0 = *(const bf16x8*)((BUF) + ((ra * 128 + kbyte) ^ ((ra & 7) << 4)));          \
      int rb = wv * 32 + 16 + l15;                                                           \
      bf16x8 a1 = *(const bf16x8*)((BUF) + ((rb * 128 + kbyte) ^ ((rb & 7) << 4)));          \
      _Pragma("unroll") for (int ct = 0; ct < 8; ++ct) {                                     \
        int rc = ct * 16 + l15;                                                              \
        bf16x8 bb = *(const bf16x8*)((BUF) + ((rc * 128 + kbyte) ^ ((rc & 7) << 4)));        \
        acc[0][ct] = __builtin_amdgcn_mfma_f32_16x16x32_bf16(a0, bb, acc[0][ct], 0, 0, 0);   \
        acc[1][ct] = __builtin_amdgcn_mfma_f32_16x16x32_bf16(a1, bb, acc[1][ct], 0, 0, 0);   \
      }                                                                                      \
    }                                                                                        \
  }

  char* buf0 = lds;
  char* buf1 = lds + 16384;

  // prologue: pair {0,1} -> registers -> both LDS buffers
  LOADPF2(0);
  PACKPF(pfA, buf0);
  PACKPF(pfB, buf1);
  __syncthreads();

#pragma unroll 1
  for (int p = 0; p < KSTEPS / 2; ++p) {
    const bool more = (p + 1) < (KSTEPS / 2);
    if (more) LOADPF2(2 * p + 2);  // paired issue overlaps both MFMA phases
    MFMAPH(buf0);                  // step 2p   (cols 0-63 of pair window)
    MFMAPH(buf1);                  // step 2p+1 (cols 64-127)
    __syncthreads();               // all waves done reading buf0/buf1
    if (more) {
      PACKPF(pfA, buf0);
      PACKPF(pfB, buf1);
    }
    __syncthreads();               // packed pair visible
  }

  // epilogue: stage 128x128 bf16 tile in LDS, then full-line linear stores
  unsigned short* lds16 = (unsigned short*)lds;
#pragma unroll
  for (int rt = 0; rt < 2; ++rt)
#pragma unroll
    for (int ct = 0; ct < 8; ++ct)
#pragma unroll
      for (int r = 0; r < 4; ++r) {
        int i = wv * 32 + rt * 16 + q * 4 + r;  // C/D: col=lane&15, row=(lane>>4)*4+reg
        int j = ct * 16 + l15;
        lds16[i * 128 + j] = f2bf_one(acc[rt][ct][r]);
      }
  __syncthreads();

  unsigned short* part = partials + (size_t)g * (NC * NC);
#pragma unroll
  for (int ii = 0; ii < 8; ++ii) {
    int off = ii * 4096 + t * 16;  // bytes
    *(uint4*)((char*)part + off) = *(const uint4*)(lds + off);
  }
#undef LOADPF2
#undef PACKPF
#undef MFMAPH
}

//==================== Kernel B: reduce + M = w @ gram (gram symmetry) ====================
// r11-proven 8-row/256-block form.
__global__ __launch_bounds__(256)
void nlm_gramw_kernel(const unsigned short* __restrict__ partials, const float* __restrict__ w,
                      unsigned short* __restrict__ Mbf) {
  __shared__ __align__(16) float glds[8 * 128];
  const int t = threadIdx.x;
  const int b  = blockIdx.x >> 4;
  const int d0 = (blockIdx.x & 15) * 8;

  const int rr = t >> 5;          // 0..7
  const int c4 = (t & 31) * 4;    // 0..124
  const unsigned short* pb =
      partials + (size_t)b * CHUNKS * (NC * NC) + (d0 + rr) * 128 + c4;
  f4v s = (f4v){0.f, 0.f, 0.f, 0.f};
  for (int chn = 0; chn < CHUNKS; ++chn) {
    u16x4 v = *(const u16x4*)(pb + (size_t)chn * (NC * NC));
    s[0] += bf2f(v[0]);
    s[1] += bf2f(v[1]);
    s[2] += bf2f(v[2]);
    s[3] += bf2f(v[3]);
  }
  s *= (1.0f / 16384.0f);
  *(f4v*)(glds + rr * 128 + c4) = s;
  __syncthreads();

  const int o  = t & 127;
  const int j0 = (t >> 7) * 4;  // 0 or 4
  float m[4] = {0.f, 0.f, 0.f, 0.f};
  for (int c = 0; c < 128; c += 4) {
    f4v wr = *(const f4v*)(w + o * 128 + c);
#pragma unroll
    for (int j = 0; j < 4; ++j) {
      f4v gv = *(const f4v*)(glds + (j0 + j) * 128 + c);
      m[j] = fmaf(wr[0], gv[0], m[j]);
      m[j] = fmaf(wr[1], gv[1], m[j]);
      m[j] = fmaf(wr[2], gv[2], m[j]);
      m[j] = fmaf(wr[3], gv[3], m[j]);
    }
  }
  uint2 pk;
  pk.x = f2bf_pack(m[0], m[1]);
  pk.y = f2bf_pack(m[2], m[3]);
  *(uint2*)(Mbf + (size_t)b * NC * NC + o * 128 + d0 + j0) = pk;
}

//==================== Kernel C: out = M @ X, staged full-row PLAIN stores ====================
__global__ __launch_bounds__(256, 2)
void nlm_out_kernel(const float* __restrict__ x, const unsigned short* __restrict__ Mbf,
                    float* __restrict__ out) {
  __shared__ __align__(16) char lds[128 * 128 * 2];  // 32 KiB: X^T tile, then out staging
  const int t = threadIdx.x;
  const int b = (NB - 1) - (blockIdx.x >> 7);  // consume LRU-warmest batches first
  const int n0 = (blockIdx.x & 127) * 128;
  const int lane = t & 63, wv = t >> 6, l15 = lane & 15, q = lane >> 4;

  bf16x8 afr[2][4];
  const unsigned short* mb = Mbf + (size_t)b * NC * NC;
#pragma unroll
  for (int rt = 0; rt < 2; ++rt)
#pragma unroll
    for (int ks = 0; ks < 4; ++ks) {
      int o = wv * 32 + rt * 16 + l15;
      afr[rt][ks] = *(const bf16x8*)(mb + o * 128 + ks * 32 + q * 8);
    }

  const float* xb = x + (size_t)b * NC * NN + n0;
#pragma unroll
  for (int i = 0; i < 2; ++i) {
    int id = t + 256 * i;
    int nb = id & 31, cb = id >> 5;
    const float* src = xb + (size_t)(cb * 8) * NN + nb * 4;
    f4v v[8];
#pragma unroll
    for (int r = 0; r < 8; ++r) v[r] = *(const f4v*)(src + (size_t)r * NN);
#pragma unroll
    for (int j = 0; j < 4; ++j) {
      int n = nb * 4 + j;
      uint4 pk;
      pk.x = f2bf_pack(v[0][j], v[1][j]);
      pk.y = f2bf_pack(v[2][j], v[3][j]);
      pk.z = f2bf_pack(v[4][j], v[5][j]);
      pk.w = f2bf_pack(v[6][j], v[7][j]);
      int byte = (n * 256 + cb * 16) ^ ((((n & 7) ^ ((n >> 3) & 7))) << 4);
      *(uint4*)(lds + byte) = pk;
    }
  }
  __syncthreads();

  f32x4 acc[2][8];
#pragma unroll
  for (int i = 0; i < 2; ++i)
#pragma unroll
    for (int j = 0; j < 8; ++j) acc[i][j] = (f32x4){0.f, 0.f, 0.f, 0.f};

#pragma unroll
  for (int ks = 0; ks < 4; ++ks) {
#pragma unroll
    for (int ct = 0; ct < 8; ++ct) {
      int n = ct * 16 + l15;
      int byte = (n * 256 + ks * 64 + q * 16) ^ ((((n & 7) ^ ((n >> 3) & 7))) << 4);
      bf16x8 bfr = *(const bf16x8*)(lds + byte);
      acc[0][ct] = __builtin_amdgcn_mfma_f32_16x16x32_bf16(afr[0][ks], bfr, acc[0][ct], 0, 0, 0);
      acc[1][ct] = __builtin_amdgcn_mfma_f32_16x16x32_bf16(afr[1][ks], bfr, acc[1][ct], 0, 0, 0);
    }
  }
  __syncthreads();  // X^T tile consumed; reuse LDS for output staging

  // Staged epilogue: two 64-row halves; each wave-instruction stores 2 full 512-B rows.
  float* lds32 = (float*)lds;
  float* ob = out + (size_t)b * NC * NN + n0;
  const int u5 = t & 31;   // 16-B unit within row (0..31)
  const int r5 = t >> 5;   // row-in-group (0..7)
#pragma unroll
  for (int rt = 0; rt < 2; ++rt) {
#pragma unroll
    for (int ct = 0; ct < 8; ++ct)
#pragma unroll
      for (int r = 0; r < 4; ++r) {
        int cr = wv * 16 + q * 4 + r;
        int col = ct * 16 + l15;
        lds32[cr * 128 + (col ^ ((cr & 7) << 2))] = acc[rt][ct][r];
      }
    __syncthreads();
#pragma unroll
    for (int rd = 0; rd < 8; ++rd) {
      int cr = rd * 8 + r5;
      int o = (cr >> 4) * 32 + rt * 16 + (cr & 15);
      f4v v = *(const f4v*)(lds32 + cr * 128 + ((u5 ^ (cr & 7)) << 2));
      *(f4v*)(ob + (size_t)o * NN + u5 * 4) = v;
    }
    __syncthreads();
  }
}

extern "C" void kernel_launch(void* const* d_in, const int* in_sizes, int n_in,
                              void* d_out, int out_size, void* d_ws, size_t ws_size,
                              hipStream_t stream) {
  const float* x = (const float*)d_in[0];
  const float* w = (const float*)d_in[1];
  float* out = (float*)d_out;

  char* wsp = (char*)d_ws;
  unsigned short* partials = (unsigned short*)wsp;              // 16 MiB (bf16)
  wsp += (size_t)NB * CHUNKS * NC * NC * 2;
  unsigned short* Mbf = (unsigned short*)wsp;                   // 512 KiB

  hipLaunchKernelGGL(nlm_gram_kernel, dim3(NB * CHUNKS), dim3(256), 0, stream,
                     x, partials);
  hipLaunchKernelGGL(nlm_gramw_kernel, dim3(NB * 16), dim3(256), 0, stream,
                     partials, w, Mbf);
  hipLaunchKernelGGL(nlm_out_kernel, dim3(NB * 128), dim3(256), 0, stream,
                     x, Mbf, out);
}

// Round 17
// 77.728 us; speedup vs baseline: 1.0413x; 1.0413x over previous
//
#include <hip/hip_runtime.h>

typedef __attribute__((ext_vector_type(8))) short bf16x8;
typedef __attribute__((ext_vector_type(4))) float f32x4;
typedef __attribute__((ext_vector_type(4))) float f4v;
typedef __attribute__((ext_vector_type(4))) unsigned short u16x4;

#define NB 16
#define NC 128
#define NN 16384
#define CHUNKS 32
#define KSTEPS 8

__device__ __forceinline__ unsigned int f2bf_pack(float lo, float hi) {
  unsigned int ulo = __float_as_uint(lo);
  unsigned int uhi = __float_as_uint(hi);
  ulo = (ulo + 0x7FFFu + ((ulo >> 16) & 1u)) >> 16;
  uhi = (uhi + 0x7FFFu + ((uhi >> 16) & 1u)) & 0xFFFF0000u;
  return ulo | uhi;
}

__device__ __forceinline__ unsigned short f2bf_one(float v) {
  unsigned int u = __float_as_uint(v);
  return (unsigned short)((u + 0x7FFFu + ((u >> 16) & 1u)) >> 16);
}

__device__ __forceinline__ float bf2f(unsigned short u) {
  return __uint_as_float(((unsigned int)u) << 16);
}

//==================== Kernel A: partial Gram per (batch, K-chunk) ====================
// r11/r15-proven: pipelined 2-deep register prefetch + LDS-staged linear-store
// epilogue. Seven alternative structures falsified; this cadence is A's floor.
__global__ __launch_bounds__(256, 2)
void nlm_gram_kernel(const float* __restrict__ x, unsigned short* __restrict__ partials) {
  __shared__ __align__(16) char lds[2 * 128 * 64 * 2];  // 2 x 16 KiB k-step buffers
  const int t = threadIdx.x;
  const int g = blockIdx.x;
  const int b  = g / CHUNKS;
  const int ch = g % CHUNKS;
  const int lane = t & 63, wv = t >> 6, l15 = lane & 15, q = lane >> 4;

  const float* xb = x + (size_t)b * NC * NN + (size_t)ch * (KSTEPS * 64);

  f32x4 acc[2][8];
#pragma unroll
  for (int i = 0; i < 2; ++i)
#pragma unroll
    for (int j = 0; j < 8; ++j) acc[i][j] = (f32x4){0.f, 0.f, 0.f, 0.f};

  int srow[4], sseg[4];
#pragma unroll
  for (int i = 0; i < 4; ++i) { int id = t + 256 * i; srow[i] = id >> 3; sseg[i] = id & 7; }

  f4v pfA[4][2], pfB[4][2];

#define LOADPF(PF, KS)                                                      \
  {                                                                         \
    _Pragma("unroll") for (int i = 0; i < 4; ++i) {                         \
      const float* src = xb + (size_t)srow[i] * NN + (KS)*64 + sseg[i] * 8; \
      PF[i][0] = *(const f4v*)src;                                          \
      PF[i][1] = *(const f4v*)(src + 4);                                    \
    }                                                                       \
  }

#define PACKPF(PF, BUF)                                                     \
  {                                                                         \
    _Pragma("unroll") for (int i = 0; i < 4; ++i) {                         \
      uint4 pk;                                                             \
      pk.x = f2bf_pack(PF[i][0][0], PF[i][0][1]);                           \
      pk.y = f2bf_pack(PF[i][0][2], PF[i][0][3]);                           \
      pk.z = f2bf_pack(PF[i][1][0], PF[i][1][1]);                           \
      pk.w = f2bf_pack(PF[i][1][2], PF[i][1][3]);                           \
      int byte = (srow[i] * 128 + sseg[i] * 16) ^ ((srow[i] & 7) << 4);     \
      *(uint4*)((BUF) + byte) = pk;                                         \
    }                                                                       \
  }

#define MFMAPH(BUF)                                                                          \
  {                                                                                          \
    _Pragma("unroll") for (int kh = 0; kh < 2; ++kh) {                                       \
      const int kbyte = kh * 64 + q * 16;                                                    \
      int ra = wv * 32 + l15;                                                                \
      bf16x8 a0 = *(const bf16x8*)((BUF) + ((ra * 128 + kbyte) ^ ((ra & 7) << 4)));          \
      int rb = wv * 32 + 16 + l15;                                                           \
      bf16x8 a1 = *(const bf16x8*)((BUF) + ((rb * 128 + kbyte) ^ ((rb & 7) << 4)));          \
      _Pragma("unroll") for (int ct = 0; ct < 8; ++ct) {                                     \
        int rc = ct * 16 + l15;                                                              \
        bf16x8 bb = *(const bf16x8*)((BUF) + ((rc * 128 + kbyte) ^ ((rc & 7) << 4)));        \
        acc[0][ct] = __builtin_amdgcn_mfma_f32_16x16x32_bf16(a0, bb, acc[0][ct], 0, 0, 0);   \
        acc[1][ct] = __builtin_amdgcn_mfma_f32_16x16x32_bf16(a1, bb, acc[1][ct], 0, 0, 0);   \
      }                                                                                      \
    }                                                                                        \
  }

  char* buf0 = lds;
  char* buf1 = lds + 16384;

  LOADPF(pfA, 0);
  PACKPF(pfA, buf0);
  LOADPF(pfB, 1);
  __syncthreads();

#pragma unroll 1
  for (int ks = 0; ks < KSTEPS; ks += 2) {
    if (ks + 2 < KSTEPS) LOADPF(pfA, ks + 2);
    MFMAPH(buf0);
    if (ks + 1 < KSTEPS) PACKPF(pfB, buf1);
    __syncthreads();
    if (ks + 1 < KSTEPS) {
      if (ks + 3 < KSTEPS) LOADPF(pfB, ks + 3);
      MFMAPH(buf1);
      if (ks + 2 < KSTEPS) PACKPF(pfA, buf0);
      __syncthreads();
    }
  }

  // epilogue: stage 128x128 bf16 tile in LDS, then full-line linear stores
  unsigned short* lds16 = (unsigned short*)lds;
#pragma unroll
  for (int rt = 0; rt < 2; ++rt)
#pragma unroll
    for (int ct = 0; ct < 8; ++ct)
#pragma unroll
      for (int r = 0; r < 4; ++r) {
        int i = wv * 32 + rt * 16 + q * 4 + r;  // C/D: col=lane&15, row=(lane>>4)*4+reg
        int j = ct * 16 + l15;
        lds16[i * 128 + j] = f2bf_one(acc[rt][ct][r]);
      }
  __syncthreads();

  unsigned short* part = partials + (size_t)g * (NC * NC);
#pragma unroll
  for (int ii = 0; ii < 8; ++ii) {
    int off = ii * 4096 + t * 16;  // bytes
    *(uint4*)((char*)part + off) = *(const uint4*)(lds + off);
  }
#undef LOADPF
#undef PACKPF
#undef MFMAPH
}

//==================== Kernel B: reduce + M = w @ gram (gram symmetry) ====================
// r11-proven 8-row/256-block form.
__global__ __launch_bounds__(256)
void nlm_gramw_kernel(const unsigned short* __restrict__ partials, const float* __restrict__ w,
                      unsigned short* __restrict__ Mbf) {
  __shared__ __align__(16) float glds[8 * 128];
  const int t = threadIdx.x;
  const int b  = blockIdx.x >> 4;
  const int d0 = (blockIdx.x & 15) * 8;

  const int rr = t >> 5;          // 0..7
  const int c4 = (t & 31) * 4;    // 0..124
  const unsigned short* pb =
      partials + (size_t)b * CHUNKS * (NC * NC) + (d0 + rr) * 128 + c4;
  f4v s = (f4v){0.f, 0.f, 0.f, 0.f};
  for (int chn = 0; chn < CHUNKS; ++chn) {
    u16x4 v = *(const u16x4*)(pb + (size_t)chn * (NC * NC));
    s[0] += bf2f(v[0]);
    s[1] += bf2f(v[1]);
    s[2] += bf2f(v[2]);
    s[3] += bf2f(v[3]);
  }
  s *= (1.0f / 16384.0f);
  *(f4v*)(glds + rr * 128 + c4) = s;
  __syncthreads();

  const int o  = t & 127;
  const int j0 = (t >> 7) * 4;  // 0 or 4
  float m[4] = {0.f, 0.f, 0.f, 0.f};
  for (int c = 0; c < 128; c += 4) {
    f4v wr = *(const f4v*)(w + o * 128 + c);
#pragma unroll
    for (int j = 0; j < 4; ++j) {
      f4v gv = *(const f4v*)(glds + (j0 + j) * 128 + c);
      m[j] = fmaf(wr[0], gv[0], m[j]);
      m[j] = fmaf(wr[1], gv[1], m[j]);
      m[j] = fmaf(wr[2], gv[2], m[j]);
      m[j] = fmaf(wr[3], gv[3], m[j]);
    }
  }
  uint2 pk;
  pk.x = f2bf_pack(m[0], m[1]);
  pk.y = f2bf_pack(m[2], m[3]);
  *(uint2*)(Mbf + (size_t)b * NC * NC + o * 128 + d0 + j0) = pk;
}

//==================== Kernel C: out = M @ X, staged full-row stores, 3 blocks/CU ====================
__global__ __launch_bounds__(256, 3)
void nlm_out_kernel(const float* __restrict__ x, const unsigned short* __restrict__ Mbf,
                    float* __restrict__ out) {
  __shared__ __align__(16) char lds[128 * 128 * 2];  // 32 KiB: X^T tile, then out staging
  const int t = threadIdx.x;
  const int b = (NB - 1) - (blockIdx.x >> 7);  // consume LRU-warmest batches first
  const int n0 = (blockIdx.x & 127) * 128;
  const int lane = t & 63, wv = t >> 6, l15 = lane & 15, q = lane >> 4;

  bf16x8 afr[2][4];
  const unsigned short* mb = Mbf + (size_t)b * NC * NC;
#pragma unroll
  for (int rt = 0; rt < 2; ++rt)
#pragma unroll
    for (int ks = 0; ks < 4; ++ks) {
      int o = wv * 32 + rt * 16 + l15;
      afr[rt][ks] = *(const bf16x8*)(mb + o * 128 + ks * 32 + q * 8);
    }

  const float* xb = x + (size_t)b * NC * NN + n0;
#pragma unroll
  for (int i = 0; i < 2; ++i) {
    int id = t + 256 * i;
    int nb = id & 31, cb = id >> 5;
    const float* src = xb + (size_t)(cb * 8) * NN + nb * 4;
    f4v v[8];
#pragma unroll
    for (int r = 0; r < 8; ++r) v[r] = *(const f4v*)(src + (size_t)r * NN);
#pragma unroll
    for (int j = 0; j < 4; ++j) {
      int n = nb * 4 + j;
      uint4 pk;
      pk.x = f2bf_pack(v[0][j], v[1][j]);
      pk.y = f2bf_pack(v[2][j], v[3][j]);
      pk.z = f2bf_pack(v[4][j], v[5][j]);
      pk.w = f2bf_pack(v[6][j], v[7][j]);
      int byte = (n * 256 + cb * 16) ^ ((((n & 7) ^ ((n >> 3) & 7))) << 4);
      *(uint4*)(lds + byte) = pk;
    }
  }
  __syncthreads();

  f32x4 acc[2][8];
#pragma unroll
  for (int i = 0; i < 2; ++i)
#pragma unroll
    for (int j = 0; j < 8; ++j) acc[i][j] = (f32x4){0.f, 0.f, 0.f, 0.f};

#pragma unroll
  for (int ks = 0; ks < 4; ++ks) {
#pragma unroll
    for (int ct = 0; ct < 8; ++ct) {
      int n = ct * 16 + l15;
      int byte = (n * 256 + ks * 64 + q * 16) ^ ((((n & 7) ^ ((n >> 3) & 7))) << 4);
      bf16x8 bfr = *(const bf16x8*)(lds + byte);
      acc[0][ct] = __builtin_amdgcn_mfma_f32_16x16x32_bf16(afr[0][ks], bfr, acc[0][ct], 0, 0, 0);
      acc[1][ct] = __builtin_amdgcn_mfma_f32_16x16x32_bf16(afr[1][ks], bfr, acc[1][ct], 0, 0, 0);
    }
  }
  __syncthreads();  // X^T tile consumed; reuse LDS for output staging

  // Staged epilogue: two 64-row halves; each wave-instruction stores 2 full 512-B rows.
  float* lds32 = (float*)lds;
  float* ob = out + (size_t)b * NC * NN + n0;
  const int u5 = t & 31;   // 16-B unit within row (0..31)
  const int r5 = t >> 5;   // row-in-group (0..7)
#pragma unroll
  for (int rt = 0; rt < 2; ++rt) {
#pragma unroll
    for (int ct = 0; ct < 8; ++ct)
#pragma unroll
      for (int r = 0; r < 4; ++r) {
        int cr = wv * 16 + q * 4 + r;
        int col = ct * 16 + l15;
        lds32[cr * 128 + (col ^ ((cr & 7) << 2))] = acc[rt][ct][r];
      }
    __syncthreads();
#pragma unroll
    for (int rd = 0; rd < 8; ++rd) {
      int cr = rd * 8 + r5;
      int o = (cr >> 4) * 32 + rt * 16 + (cr & 15);
      f4v v = *(const f4v*)(lds32 + cr * 128 + ((u5 ^ (cr & 7)) << 2));
      *(f4v*)(ob + (size_t)o * NN + u5 * 4) = v;
    }
    __syncthreads();
  }
}

extern "C" void kernel_launch(void* const* d_in, const int* in_sizes, int n_in,
                              void* d_out, int out_size, void* d_ws, size_t ws_size,
                              hipStream_t stream) {
  const float* x = (const float*)d_in[0];
  const float* w = (const float*)d_in[1];
  float* out = (float*)d_out;

  char* wsp = (char*)d_ws;
  unsigned short* partials = (unsigned short*)wsp;              // 16 MiB (bf16)
  wsp += (size_t)NB * CHUNKS * NC * NC * 2;
  unsigned short* Mbf = (unsigned short*)wsp;                   // 512 KiB

  hipLaunchKernelGGL(nlm_gram_kernel, dim3(NB * CHUNKS), dim3(256), 0, stream,
                     x, partials);
  hipLaunchKernelGGL(nlm_gramw_kernel, dim3(NB * 16), dim3(256), 0, stream,
                     partials, w, Mbf);
  hipLaunchKernelGGL(nlm_out_kernel, dim3(NB * 128), dim3(256), 0, stream,
                     x, Mbf, out);
}